// Round 6
// baseline (1739.178 us; speedup 1.0000x reference)
//
#include <hip/hip_runtime.h>

#define T_SEQ   1024
#define INDIM   6
#define HDIM    64
#define NPRED   10
#define CHNK    64       // x staging chunk (steps)
#define S0      72       // LDS row stride (elements) for h rows
#define NROWS   16       // batch rows per workgroup (grid 256 = 1 block/CU)
#define RD      16       // h0 ring depth = 2 windows
#define WIN     8        // steps per window (A<->B sync cadence)

typedef __bf16         bf16x8 __attribute__((ext_vector_type(8)));
typedef float          f32x4  __attribute__((ext_vector_type(4)));
typedef float          f32x2  __attribute__((ext_vector_type(2)));

// D = A*B + C with A = weight frag, B = h frag  ->  D[m=unit][n=batch row]
#define MFMA16(a, b, c) __builtin_amdgcn_mfma_f32_16x16x32_bf16((a), (b), (c), 0, 0, 0)
// compiler-only fence: stops TBAA from reordering LDS short-writes vs bf16 reads
#define MEMBAR() asm volatile("" ::: "memory")

static __device__ __forceinline__ float bf2f(unsigned short b) {
  union { unsigned int u; float f; } v; v.u = ((unsigned int)b) << 16; return v.f;
}
// Native RNE f32->bf16 (ISel pairs these into v_cvt_pk_bf16_f32 on gfx950).
static __device__ __forceinline__ unsigned short f2bf(float f) {
  union { __bf16 b; unsigned short u; } v; v.b = (__bf16)f; return v.u;
}

// R6: barrier-free recurrence. 2 waves/block (A = layer0, B = layer1), each
// wave computes ALL 64 units x 16 rows (16 MFMA tiles, 16 cells/lane) so the
// per-step h write->read is INTRA-WAVE (LDS DS ops are in-order per wave; no
// barrier needed, only a compiler memory fence). A->B handoff via a 16-slot
// h0 ring with one __syncthreads per 8-step window (A produces window w while
// B consumes window w-1; slot halves are disjoint). 129 cheap 2-wave barriers
// replace 1024 8-wave barriers. Weights register-resident (B bias from LDS
// broadcast). All MFMA chain orders / act4 math / FC scalar order preserved
// exactly (bit-exact canary: absmax must stay 0.0009765625).
template <bool F32>
__global__ __launch_bounds__(128, 1)
void lstm2_pipe(const void* __restrict__ xv,
                const void* __restrict__ Wih0v,
                const void* __restrict__ Whh0v,
                const void* __restrict__ bih0v,
                const void* __restrict__ bhh0v,
                const void* __restrict__ Wih1v,
                const void* __restrict__ Whh1v,
                const void* __restrict__ bih1v,
                const void* __restrict__ bhh1v,
                const void* __restrict__ fcwv,
                const void* __restrict__ fcbv,
                void* __restrict__ outv)
{
  // ---- dtype sniff (uniform) ----
  {
    const unsigned short* w0u = (const unsigned short*)Wih0v;
    int votes = 0;
#pragma unroll
    for (int i = 0; i < 16; ++i) {
      const unsigned e = (w0u[2 * i] >> 7) & 0xFF;
      votes += (e >= 0x80 || e <= 0x40) ? 1 : 0;
    }
    if ((votes >= 4) != F32) return;
  }

  __shared__ __align__(16) unsigned short RING[RD * NROWS * S0];   // h0 ring (36.9KB)
  __shared__ __align__(16) unsigned short H1B[2 * NROWS * S0];     // h1 dbuf
  __shared__ __align__(16) unsigned short XB2[NROWS * CHNK * 8];   // x chunk, swizzled (16KB)
  __shared__ __align__(16) float BIAS1[4 * HDIM];                  // layer1 bias (f32)
  __shared__ __align__(16) unsigned short XD[NROWS * 8];           // decoder x feedback
  __shared__ __align__(16) unsigned short ZPAD[8];
  __shared__ __align__(16) unsigned short FCW[INDIM * HDIM];
  __shared__ float FCB[INDIM];

  const int tid   = threadIdx.x;        // 0..127
  const int lane  = tid & 63;
  const bool isA  = (tid < 64);
  const int  q    = lane >> 4;
  const int  n    = lane & 15;          // batch row owned by this lane (D col)
  const int rbase = blockIdx.x * NROWS;

  auto ld1 = [&](const void* p, int i) -> float {
    if constexpr (F32) return ((const float*)p)[i];
    else               return bf2f(((const unsigned short*)p)[i]);
  };
  auto ld8 = [&](const void* W, int off) -> bf16x8 {
    union { unsigned short us[8]; bf16x8 v; } t;
    if constexpr (F32) {
      const float* p = (const float*)W + off;
#pragma unroll
      for (int j = 0; j < 8; ++j) t.us[j] = f2bf(p[j]);
    } else {
      t.v = *(const bf16x8*)((const unsigned short*)W + off);
    }
    return t.v;
  };

  // ---- init (both waves; consumed after first barrier) ----
  {
    const int4 z = {0, 0, 0, 0};
    for (int i = tid; i < (2 * NROWS * S0) / 8; i += 128) ((int4*)H1B)[i] = z; // h1(-1)=0
    if (tid < (NROWS * 8) / 8) ((int4*)XD)[tid] = z;
    if (tid < 8) ZPAD[tid] = 0;
  }
  for (int i = tid; i < 4 * HDIM; i += 128) BIAS1[i] = ld1(bih1v, i) + ld1(bhh1v, i);
  for (int i = tid; i < INDIM * HDIM; i += 128) {
    if constexpr (F32) FCW[i] = f2bf(((const float*)fcwv)[i]);
    else               FCW[i] = ((const unsigned short*)fcwv)[i];
  }
  if (tid < INDIM) {
    if constexpr (F32) FCB[tid] = ((const float*)fcbv)[tid];
    else               FCB[tid] = bf2f(((const unsigned short*)fcbv)[tid]);
  }

  const int aOff = n * S0 + 8 * q;      // h frag (B-operand): row n, k 8q..8q+7
  const int hW   = n * S0 + 4 * q;      // packed h-write base (caller adds 16*j)

  // 7-trans combined-rcp cell update, packed-f32 elementwise, cvt_pk bf16,
  // one b64 write. Math identical to R5 (bit-exact).
  const f32x2 C1   = {-1.442695040888963f, -1.442695040888963f};
  const f32x2 C2   = {-2.885390081777927f, -2.885390081777927f};
  const f32x2 onep = {1.0f, 1.0f};

  auto act4 = [&](const f32x4 gI, const f32x4 gF, const f32x4 gG, const f32x4 gO,
                  unsigned short* dst, f32x2* cc) {
    unsigned int w2[2];
#pragma unroll
    for (int p = 0; p < 2; ++p) {
      f32x2 vI, vF, vG, vO;
      vI.x = gI[2 * p]; vI.y = gI[2 * p + 1];
      vF.x = gF[2 * p]; vF.y = gF[2 * p + 1];
      vG.x = gG[2 * p]; vG.y = gG[2 * p + 1];
      vO.x = gO[2 * p]; vO.y = gO[2 * p + 1];
      const f32x2 aF = vF * C1;
      const f32x2 aI = vI * C1;
      const f32x2 aG = vG * C2;
      const f32x2 aO = vO * C1;
      f32x2 Ae, Be, Ge, Oe;
      Ae.x = __builtin_amdgcn_exp2f(aF.x); Ae.y = __builtin_amdgcn_exp2f(aF.y);
      Be.x = __builtin_amdgcn_exp2f(aI.x); Be.y = __builtin_amdgcn_exp2f(aI.y);
      Ge.x = __builtin_amdgcn_exp2f(aG.x); Ge.y = __builtin_amdgcn_exp2f(aG.y);
      Oe.x = __builtin_amdgcn_exp2f(aO.x); Oe.y = __builtin_amdgcn_exp2f(aO.y);
      const f32x2 M1 = (onep + Be) * (onep + Ge);
      const f32x2 t2 = onep + Ae;
      const f32x2 nm = cc[p] * M1 + (onep - Ge) * t2;
      const f32x2 den = t2 * M1;
      f32x2 rd; rd.x = __builtin_amdgcn_rcpf(den.x); rd.y = __builtin_amdgcn_rcpf(den.y);
      const f32x2 cn = nm * rd;
      cc[p] = cn;
      const f32x2 aE = cn * C2;
      f32x2 Ee; Ee.x = __builtin_amdgcn_exp2f(aE.x); Ee.y = __builtin_amdgcn_exp2f(aE.y);
      const f32x2 dh = (onep + Ee) * (onep + Oe);
      f32x2 rh; rh.x = __builtin_amdgcn_rcpf(dh.x); rh.y = __builtin_amdgcn_rcpf(dh.y);
      const f32x2 hv = (onep - Ee) * rh;
      w2[p] = (unsigned int)f2bf(hv.x) | ((unsigned int)f2bf(hv.y) << 16);
    }
    uint2 pk; pk.x = w2[0]; pk.y = w2[1];
    *(uint2*)(dst + hW) = pk;
  };

  // stage x chunk [t0c, t0c+CHNK) into XB2[row][t^(row&7)][8] (A-wave only)
  auto stage = [&](int t0c) {
    for (int c = lane; c < NROWS * CHNK; c += 64) {
      const int row = c >> 6;          // CHNK=64
      const int t   = c & (CHNK - 1);
      int4 o;
      if constexpr (F32) {
        const float* p = (const float*)xv + ((size_t)(rbase + row) * T_SEQ + (t0c + t)) * INDIM;
        const float2 v0 = *(const float2*)(p);
        const float2 v1 = *(const float2*)(p + 2);
        const float2 v2 = *(const float2*)(p + 4);
        union { unsigned short us[8]; int4 v; } tt;
        tt.us[0] = f2bf(v0.x); tt.us[1] = f2bf(v0.y);
        tt.us[2] = f2bf(v1.x); tt.us[3] = f2bf(v1.y);
        tt.us[4] = f2bf(v2.x); tt.us[5] = f2bf(v2.y);
        tt.us[6] = 0;          tt.us[7] = 0;
        o = tt.v;
      } else {
        const unsigned short* p = (const unsigned short*)xv
            + ((size_t)(rbase + row) * T_SEQ + (t0c + t)) * INDIM;
        o.x = *(const unsigned int*)(p);
        o.y = *(const unsigned int*)(p + 2);
        o.z = *(const unsigned int*)(p + 4);
        o.w = 0;
      }
      *(int4*)((char*)XB2 + (((size_t)row * CHNK) + (t ^ (row & 7))) * 16) = o;
    }
    MEMBAR();
  };

  if (isA) {
    // ================= layer-0 engine (1 wave, all 64 units) =================
    bf16x8 W0A[16], W1A[16], WXA[16]; f32x4 bvA[16];
#pragma unroll
    for (int g = 0; g < 4; ++g) {
#pragma unroll
      for (int j = 0; j < 4; ++j) {
        const int gj = g * 4 + j;
        const int rowW = 64 * g + 16 * j + n;
        W0A[gj] = ld8(Whh0v, rowW * HDIM + 8 * q);
        W1A[gj] = ld8(Whh0v, rowW * HDIM + 32 + 8 * q);
        union { unsigned short us[8]; bf16x8 v; } t2;
#pragma unroll
        for (int jj = 0; jj < 8; ++jj) t2.us[jj] = 0;
        if (q == 0) {
#pragma unroll
          for (int jj = 0; jj < INDIM; ++jj) t2.us[jj] = f2bf(ld1(Wih0v, rowW * INDIM + jj));
        }
        WXA[gj] = t2.v;
        const int bb = 64 * g + 16 * j + 4 * q;
        f32x4 bv;
#pragma unroll
        for (int jj = 0; jj < 4; ++jj) bv[jj] = ld1(bih0v, bb + jj) + ld1(bhh0v, bb + jj);
        bvA[gj] = bv;
      }
    }

    f32x2 ccA[8];
#pragma unroll
    for (int i = 0; i < 8; ++i) ccA[i] = (f32x2){0.f, 0.f};
    bf16x8 f0, f1;
    {
      union { unsigned short us[8]; bf16x8 v; } z;
#pragma unroll
      for (int jj = 0; jj < 8; ++jj) z.us[jj] = 0;
      f0 = z.v; f1 = z.v;                      // h0(-1) = 0
    }

#pragma unroll 1
    for (int w = 0; w <= T_SEQ / WIN; ++w) {
      __syncthreads();                          // window handoff (129 total)
      if (w < T_SEQ / WIN) {
        const int tb = w * WIN;
        if ((tb & (CHNK - 1)) == 0) stage(tb);  // intra-wave only, no barrier
#pragma unroll 1
        for (int s = 0; s < WIN; ++s) {
          const int t = tb + s;
          MEMBAR();
          bf16x8 xf;
          if (q == 0) xf = *(const bf16x8*)((const char*)XB2
                           + (((size_t)n * CHNK) + ((t & (CHNK - 1)) ^ (n & 7))) * 16);
          else        xf = *(const bf16x8*)ZPAD;
          unsigned short* dst = &RING[(t & (RD - 1)) * (NROWS * S0)];
          bf16x8 f0n, f1n;
#pragma unroll
          for (int j = 0; j < 4; ++j) {
            f32x4 g0 = MFMA16(W0A[0*4+j], f0, bvA[0*4+j]); g0 = MFMA16(W1A[0*4+j], f1, g0); g0 = MFMA16(WXA[0*4+j], xf, g0);
            f32x4 g1 = MFMA16(W0A[1*4+j], f0, bvA[1*4+j]); g1 = MFMA16(W1A[1*4+j], f1, g1); g1 = MFMA16(WXA[1*4+j], xf, g1);
            f32x4 g2 = MFMA16(W0A[2*4+j], f0, bvA[2*4+j]); g2 = MFMA16(W1A[2*4+j], f1, g2); g2 = MFMA16(WXA[2*4+j], xf, g2);
            f32x4 g3 = MFMA16(W0A[3*4+j], f0, bvA[3*4+j]); g3 = MFMA16(W1A[3*4+j], f1, g3); g3 = MFMA16(WXA[3*4+j], xf, g3);
            act4(g0, g1, g2, g3, dst + 16 * j, &ccA[2 * j]);
            if (j == 1) { MEMBAR(); f0n = *(const bf16x8*)(dst + aOff); }  // k 0..31 ready
          }
          MEMBAR();
          f1n = *(const bf16x8*)(dst + aOff + 32);
          f0 = f0n; f1 = f1n;
        }
      }
    }
    // seed decoder x feedback with x(1023) (chunk slot CHNK-1, swizzled)
    if (lane < 16)
      *(int4*)(XD + lane * 8) = *(const int4*)((const char*)XB2
          + (((size_t)lane * CHNK) + ((CHNK - 1) ^ (lane & 7))) * 16);
    // ---- decoder, engine A: { bar; compute h0; bar } per step ----
    unsigned short* H0d = &RING[(RD - 1) * (NROWS * S0)];   // h0(1023) slot
#pragma unroll 1
    for (int d = 0; d < NPRED; ++d) {
      __syncthreads();                      // (1) XD(d-1) visible
      MEMBAR();
      const bf16x8 fa0 = *(const bf16x8*)(H0d + aOff);
      const bf16x8 fa1 = *(const bf16x8*)(H0d + aOff + 32);
      bf16x8 fx;
      if (q == 0) fx = *(const bf16x8*)((const char*)XD + n * 16);
      else        fx = *(const bf16x8*)ZPAD;
#pragma unroll
      for (int j = 0; j < 4; ++j) {
        f32x4 g0 = MFMA16(W0A[0*4+j], fa0, bvA[0*4+j]); g0 = MFMA16(W1A[0*4+j], fa1, g0); g0 = MFMA16(WXA[0*4+j], fx, g0);
        f32x4 g1 = MFMA16(W0A[1*4+j], fa0, bvA[1*4+j]); g1 = MFMA16(W1A[1*4+j], fa1, g1); g1 = MFMA16(WXA[1*4+j], fx, g1);
        f32x4 g2 = MFMA16(W0A[2*4+j], fa0, bvA[2*4+j]); g2 = MFMA16(W1A[2*4+j], fa1, g2); g2 = MFMA16(WXA[2*4+j], fx, g2);
        f32x4 g3 = MFMA16(W0A[3*4+j], fa0, bvA[3*4+j]); g3 = MFMA16(W1A[3*4+j], fa1, g3); g3 = MFMA16(WXA[3*4+j], fx, g3);
        act4(g0, g1, g2, g3, H0d + 16 * j, &ccA[2 * j]);
      }
      __syncthreads();                      // (2) h0(d) visible to B
    }
  } else {
    // ================= layer-1 engine (1 wave, all 64 units) =================
    bf16x8 Wi0[16], Wi1[16], Wh0[16], Wh1[16];
#pragma unroll
    for (int g = 0; g < 4; ++g) {
#pragma unroll
      for (int j = 0; j < 4; ++j) {
        const int gj = g * 4 + j;
        const int rowW = 64 * g + 16 * j + n;
        Wi0[gj] = ld8(Wih1v, rowW * HDIM + 8 * q);
        Wi1[gj] = ld8(Wih1v, rowW * HDIM + 32 + 8 * q);
        Wh0[gj] = ld8(Whh1v, rowW * HDIM + 8 * q);
        Wh1[gj] = ld8(Whh1v, rowW * HDIM + 32 + 8 * q);
      }
    }
    f32x2 ccB[8];
#pragma unroll
    for (int i = 0; i < 8; ++i) ccB[i] = (f32x2){0.f, 0.f};

#pragma unroll 1
    for (int w = 0; w <= T_SEQ / WIN; ++w) {
      __syncthreads();                          // window handoff
      if (w >= 1) {
        const int tb = (w - 1) * WIN;           // consume previous window
#pragma unroll 1
        for (int s = 0; s < WIN; ++s) {
          const int t = tb + s;
          MEMBAR();
          const unsigned short* h0s = &RING[(t & (RD - 1)) * (NROWS * S0)];
          const unsigned short* h1s = &H1B[((t + 1) & 1) * (NROWS * S0)];  // h1(t-1)
          unsigned short*       dst = &H1B[(t & 1) * (NROWS * S0)];        // h1(t)
          const bf16x8 a0 = *(const bf16x8*)(h0s + aOff);
          const bf16x8 a1 = *(const bf16x8*)(h0s + aOff + 32);
          const bf16x8 b0 = *(const bf16x8*)(h1s + aOff);
          const bf16x8 b1 = *(const bf16x8*)(h1s + aOff + 32);
#pragma unroll
          for (int j = 0; j < 4; ++j) {
            const f32x4 c0 = *(const f32x4*)(&BIAS1[0 * 64 + 16 * j + 4 * q]);
            const f32x4 c1 = *(const f32x4*)(&BIAS1[1 * 64 + 16 * j + 4 * q]);
            const f32x4 c2 = *(const f32x4*)(&BIAS1[2 * 64 + 16 * j + 4 * q]);
            const f32x4 c3 = *(const f32x4*)(&BIAS1[3 * 64 + 16 * j + 4 * q]);
            f32x4 g0 = MFMA16(Wi0[0*4+j], a0, c0); g0 = MFMA16(Wi1[0*4+j], a1, g0); g0 = MFMA16(Wh0[0*4+j], b0, g0); g0 = MFMA16(Wh1[0*4+j], b1, g0);
            f32x4 g1 = MFMA16(Wi0[1*4+j], a0, c1); g1 = MFMA16(Wi1[1*4+j], a1, g1); g1 = MFMA16(Wh0[1*4+j], b0, g1); g1 = MFMA16(Wh1[1*4+j], b1, g1);
            f32x4 g2 = MFMA16(Wi0[2*4+j], a0, c2); g2 = MFMA16(Wi1[2*4+j], a1, g2); g2 = MFMA16(Wh0[2*4+j], b0, g2); g2 = MFMA16(Wh1[2*4+j], b1, g2);
            f32x4 g3 = MFMA16(Wi0[3*4+j], a0, c3); g3 = MFMA16(Wi1[3*4+j], a1, g3); g3 = MFMA16(Wh0[3*4+j], b0, g3); g3 = MFMA16(Wh1[3*4+j], b1, g3);
            act4(g0, g1, g2, g3, dst + 16 * j, &ccB[2 * j]);
          }
        }
      }
    }
    // ---- decoder, engine B: { bar; bar; compute h1 + FC head } per step ----
    int p = 1;                                  // h1(1023) parity
#pragma unroll 1
    for (int d = 0; d < NPRED; ++d) {
      __syncthreads();                      // (1)
      __syncthreads();                      // (2) h0(d) ready
      MEMBAR();
      const unsigned short* h0s = &RING[(RD - 1) * (NROWS * S0)];
      const unsigned short* h1s = &H1B[p * (NROWS * S0)];
      unsigned short*       dst = &H1B[(p ^ 1) * (NROWS * S0)];
      const bf16x8 a0 = *(const bf16x8*)(h0s + aOff);
      const bf16x8 a1 = *(const bf16x8*)(h0s + aOff + 32);
      const bf16x8 b0 = *(const bf16x8*)(h1s + aOff);
      const bf16x8 b1 = *(const bf16x8*)(h1s + aOff + 32);
#pragma unroll
      for (int j = 0; j < 4; ++j) {
        const f32x4 c0 = *(const f32x4*)(&BIAS1[0 * 64 + 16 * j + 4 * q]);
        const f32x4 c1 = *(const f32x4*)(&BIAS1[1 * 64 + 16 * j + 4 * q]);
        const f32x4 c2 = *(const f32x4*)(&BIAS1[2 * 64 + 16 * j + 4 * q]);
        const f32x4 c3 = *(const f32x4*)(&BIAS1[3 * 64 + 16 * j + 4 * q]);
        f32x4 g0 = MFMA16(Wi0[0*4+j], a0, c0); g0 = MFMA16(Wi1[0*4+j], a1, g0); g0 = MFMA16(Wh0[0*4+j], b0, g0); g0 = MFMA16(Wh1[0*4+j], b1, g0);
        f32x4 g1 = MFMA16(Wi0[1*4+j], a0, c1); g1 = MFMA16(Wi1[1*4+j], a1, g1); g1 = MFMA16(Wh0[1*4+j], b0, g1); g1 = MFMA16(Wh1[1*4+j], b1, g1);
        f32x4 g2 = MFMA16(Wi0[2*4+j], a0, c2); g2 = MFMA16(Wi1[2*4+j], a1, g2); g2 = MFMA16(Wh0[2*4+j], b0, g2); g2 = MFMA16(Wh1[2*4+j], b1, g2);
        f32x4 g3 = MFMA16(Wi0[3*4+j], a0, c3); g3 = MFMA16(Wi1[3*4+j], a1, g3); g3 = MFMA16(Wh0[3*4+j], b0, g3); g3 = MFMA16(Wh1[3*4+j], b1, g3);
        act4(g0, g1, g2, g3, dst + 16 * j, &ccB[2 * j]);
      }
      MEMBAR();
      // FC head + feedback (scalar, same op order as R5 -> bit-exact)
#pragma unroll 1
      for (int e = lane; e < 96; e += 64) {
        const int row = e / INDIM;
        const int k   = e - row * INDIM;
        const unsigned short* h1row = dst + row * S0;
        const int4* hp = (const int4*)h1row;
        const int4* wp = (const int4*)(&FCW[k * HDIM]);
        float sacc = FCB[k];
#pragma unroll
        for (int i8 = 0; i8 < 8; ++i8) {
          const int4 hv = hp[i8];
          const int4 wv2 = wp[i8];
          const unsigned int hu[4] = {(unsigned)hv.x, (unsigned)hv.y, (unsigned)hv.z, (unsigned)hv.w};
          const unsigned int wu[4] = {(unsigned)wv2.x, (unsigned)wv2.y, (unsigned)wv2.z, (unsigned)wv2.w};
#pragma unroll
          for (int k2 = 0; k2 < 4; ++k2) {
            union { unsigned int uu; float ff; } hl, hh2, wl, wh;
            hl.uu = hu[k2] << 16; hh2.uu = hu[k2] & 0xFFFF0000u;
            wl.uu = wu[k2] << 16; wh.uu  = wu[k2] & 0xFFFF0000u;
            sacc += hl.ff * wl.ff + hh2.ff * wh.ff;
          }
        }
        const unsigned short pb = f2bf(sacc);
        const size_t idx = (size_t)(rbase + row) * (NPRED * INDIM) + (size_t)d * INDIM + k;
        if constexpr (F32) ((float*)outv)[idx] = sacc;
        else               ((unsigned short*)outv)[idx] = pb;
        XD[row * 8 + k] = pb;
      }
      p ^= 1;
    }
  }
}

extern "C" void kernel_launch(void* const* d_in, const int* in_sizes, int n_in,
                              void* d_out, int out_size, void* d_ws, size_t ws_size,
                              hipStream_t stream) {
  (void)in_sizes; (void)n_in; (void)d_ws; (void)ws_size; (void)out_size;
  const void* x    = d_in[0];
  const void* Wih0 = d_in[1];
  const void* Whh0 = d_in[2];
  const void* bih0 = d_in[3];
  const void* bhh0 = d_in[4];
  const void* Wih1 = d_in[5];
  const void* Whh1 = d_in[6];
  const void* bih1 = d_in[7];
  const void* bhh1 = d_in[8];
  const void* fcw  = d_in[9];
  const void* fcb  = d_in[10];
  // Exactly one instance does the work (device-side dtype sniff).
  lstm2_pipe<true><<<dim3(4096 / NROWS), dim3(128), 0, stream>>>(
      x, Wih0, Whh0, bih0, bhh0, Wih1, Whh1, bih1, bhh1, fcw, fcb, d_out);
  lstm2_pipe<false><<<dim3(4096 / NROWS), dim3(128), 0, stream>>>(
      x, Wih0, Whh0, bih0, bhh0, Wih1, Whh1, bih1, bhh1, fcw, fcb, d_out);
}

// Round 7
// 1005.620 us; speedup vs baseline: 1.7295x; 1.7295x over previous
//
#include <hip/hip_runtime.h>

#define T_SEQ   1024
#define INDIM   6
#define HDIM    64
#define NPRED   10
#define CHNK    128
#define S0      72       // LDS row stride (elements) for h buffers (h-only)
#define NROWS   16       // batch rows per workgroup (grid 256 = 1 block/CU)

typedef __bf16         bf16x8 __attribute__((ext_vector_type(8)));
typedef float          f32x4  __attribute__((ext_vector_type(4)));
typedef float          f32x2  __attribute__((ext_vector_type(2)));
typedef unsigned short us4    __attribute__((ext_vector_type(4)));

// D = A*B + C with A = weight frag, B = h frag  ->  D[m=unit][n=batch row]
#define MFMA16(a, b, c) __builtin_amdgcn_mfma_f32_16x16x32_bf16((a), (b), (c), 0, 0, 0)

static __device__ __forceinline__ float bf2f(unsigned short b) {
  union { unsigned int u; float f; } v; v.u = ((unsigned int)b) << 16; return v.f;
}
// Native RNE f32->bf16 (ISel pairs these into v_cvt_pk_bf16_f32 on gfx950).
static __device__ __forceinline__ unsigned short f2bf(float f) {
  union { __bf16 b; unsigned short u; } v; v.b = (__bf16)f; return v.u;
}

// R7 = R5 skeleton (layer-pipelined, 1 barrier/encoder step, 512 thr,
// XB2 swizzled direct-x-MFMA, S0=72, setprio) with two bit-exact issue cuts:
//  - host-side dtype dispatch (single launch; sniff kept as fallback guard)
//  - MFMA bias C-init loaded per step from LDS (ds_read_b128, broadcast,
//    laundered index defeats hoisting) instead of ~16 v_mov VGPR copies
//    per wave-step. Same values -> bit-exact (absmax must stay 0.0009765625).
template <bool F32>
__global__ __launch_bounds__(512, 2)
void lstm2_pipe(const void* __restrict__ xv,
                const void* __restrict__ Wih0v,
                const void* __restrict__ Whh0v,
                const void* __restrict__ bih0v,
                const void* __restrict__ bhh0v,
                const void* __restrict__ Wih1v,
                const void* __restrict__ Whh1v,
                const void* __restrict__ bih1v,
                const void* __restrict__ bhh1v,
                const void* __restrict__ fcwv,
                const void* __restrict__ fcbv,
                void* __restrict__ outv)
{
  // ---- dtype sniff (uniform; guards the dual-launch fallback path) ----
  {
    const unsigned short* w0u = (const unsigned short*)Wih0v;
    int votes = 0;
#pragma unroll
    for (int i = 0; i < 16; ++i) {
      const unsigned e = (w0u[2 * i] >> 7) & 0xFF;
      votes += (e >= 0x80 || e <= 0x40) ? 1 : 0;
    }
    if ((votes >= 4) != F32) return;
  }

  // A0[b]: [row][k]: k 0..63 = h0 (unit-major), 64..71 pad.
  __shared__ __align__(16) unsigned short A0[2][NROWS * S0];
  __shared__ __align__(16) unsigned short A1[2][NROWS * S0];
  __shared__ __align__(16) unsigned short XB2[NROWS * CHNK * 8];  // [row][t^(row&7)][8]
  __shared__ __align__(16) unsigned short XD[NROWS * 8];          // decoder x feedback
  __shared__ __align__(16) unsigned short ZPAD[8];                // 16B of zeros
  __shared__ __align__(16) unsigned short FCW[INDIM * HDIM];
  __shared__ __align__(16) float BS0[4 * HDIM];                   // layer0 bias (f32)
  __shared__ __align__(16) float BS1[4 * HDIM];                   // layer1 bias (f32)
  __shared__ float FCB[INDIM];

  const int tid   = threadIdx.x;
  const int lane  = tid & 63;
  const int wave  = tid >> 6;
  const bool isA  = (wave < 4);
  const int  wv4  = wave & 3;
  const int  q    = lane >> 4;
  const int  n    = lane & 15;          // batch row owned by this lane (D col)
  const int  u    = 16 * wv4 + n;       // index used for W/bias row addressing
  const int rbase = blockIdx.x * NROWS;

  auto ld1 = [&](const void* p, int i) -> float {
    if constexpr (F32) return ((const float*)p)[i];
    else               return bf2f(((const unsigned short*)p)[i]);
  };

  {
    unsigned short* p0 = &A0[0][0];
    unsigned short* p1 = &A1[0][0];
    for (int i = tid; i < 2 * NROWS * S0; i += 512) { p0[i] = 0; p1[i] = 0; }
    for (int i = tid; i < NROWS * 8; i += 512) XD[i] = 0;
    if (tid < 8) ZPAD[tid] = 0;
  }
  for (int i = tid; i < 4 * HDIM; i += 512) {
    BS0[i] = ld1(bih0v, i) + ld1(bhh0v, i);
    BS1[i] = ld1(bih1v, i) + ld1(bhh1v, i);
  }
  for (int i = tid; i < INDIM * HDIM; i += 512) {
    if constexpr (F32) FCW[i] = f2bf(((const float*)fcwv)[i]);
    else               FCW[i] = ((const unsigned short*)fcwv)[i];
  }
  if (tid < INDIM) {
    if constexpr (F32) FCB[tid] = ((const float*)fcbv)[tid];
    else               FCB[tid] = bf2f(((const unsigned short*)fcbv)[tid]);
  }

  auto ld8 = [&](const void* W, int off) -> bf16x8 {
    union { unsigned short us[8]; bf16x8 v; } t;
    if constexpr (F32) {
      const float* p = (const float*)W + off;
#pragma unroll
      for (int j = 0; j < 8; ++j) t.us[j] = f2bf(p[j]);
    } else {
      t.v = *(const bf16x8*)((const unsigned short*)W + off);
    }
    return t.v;
  };

  // stage chunk [t0c, t0c+CHNK) into XB2: per (row,t): 6 x-values + 2 zeros,
  // swizzled slot t^(row&7). t fast-varying across lanes -> coalesced global.
  auto load_chunk = [&](int t0c) {
    for (int c = tid; c < NROWS * CHNK; c += 512) {
      const int row = c >> 7;          // 0..15
      const int t   = c & (CHNK - 1);  // 0..127
      int4 o;
      if constexpr (F32) {
        const float* p = (const float*)xv + ((size_t)(rbase + row) * T_SEQ + (t0c + t)) * INDIM;
        const float2 v0 = *(const float2*)(p);
        const float2 v1 = *(const float2*)(p + 2);
        const float2 v2 = *(const float2*)(p + 4);
        union { unsigned short us[8]; int4 v; } tt;
        tt.us[0] = f2bf(v0.x); tt.us[1] = f2bf(v0.y);
        tt.us[2] = f2bf(v1.x); tt.us[3] = f2bf(v1.y);
        tt.us[4] = f2bf(v2.x); tt.us[5] = f2bf(v2.y);
        tt.us[6] = 0;          tt.us[7] = 0;
        o = tt.v;
      } else {
        const unsigned short* p = (const unsigned short*)xv
            + ((size_t)(rbase + row) * T_SEQ + (t0c + t)) * INDIM;
        o.x = *(const unsigned int*)(p);
        o.y = *(const unsigned int*)(p + 2);
        o.z = *(const unsigned int*)(p + 4);
        o.w = 0;
      }
      *(int4*)((char*)XB2 + (((size_t)row * CHNK) + (t ^ (row & 7))) * 16) = o;
    }
  };

  load_chunk(0);

  // decoder FC/feedback mapping (tid-based, barrier-protected)
  const int dxr = tid / INDIM;                 // valid for tid < 96
  const int dxk = tid - dxr * INDIM;

  __syncthreads();   // covers zero-init + FCW + BS + chunk 0

  const int aOff  = n * S0 + 8 * q;               // h frag (B-operand): row n, k 8q..
  const int hOffW = n * S0 + 16 * wv4 + 4 * q;    // packed h-write: row n, units 4q..4q+3
  const int bOff  = 16 * wv4 + 4 * q;             // bias vector base within gate block

  // x B-operand source: q==0 lanes read XB2 row n (swizzled), q>0 broadcast ZPAD
  auto xsrc_at = [&](int tc) -> const char* {
    return (q == 0)
        ? ((const char*)XB2 + (((size_t)n * CHNK) + (tc ^ (n & 7))) * 16)
        : (const char*)ZPAD;
  };

  // cell state as two f32 pairs (cells 0,1 | 2,3) so act math stays packed
  f32x2 cc2[2]; cc2[0] = (f32x2){0.f, 0.f}; cc2[1] = (f32x2){0.f, 0.f};

  // 7-trans combined-rcp cell update, packed-f32 (v_pk_*) elementwise math,
  // native cvt_pk bf16 packing, one b64 h-write.
  const f32x2 C1   = {-1.442695040888963f, -1.442695040888963f};
  const f32x2 C2   = {-2.885390081777927f, -2.885390081777927f};
  const f32x2 onep = {1.0f, 1.0f};

  auto act4 = [&](const f32x4 gI, const f32x4 gF, const f32x4 gG, const f32x4 gO,
                  unsigned short* dst) {
    unsigned int w2[2];
#pragma unroll
    for (int p = 0; p < 2; ++p) {
      f32x2 vI, vF, vG, vO;
      vI.x = gI[2 * p]; vI.y = gI[2 * p + 1];
      vF.x = gF[2 * p]; vF.y = gF[2 * p + 1];
      vG.x = gG[2 * p]; vG.y = gG[2 * p + 1];
      vO.x = gO[2 * p]; vO.y = gO[2 * p + 1];
      const f32x2 aF = vF * C1;
      const f32x2 aI = vI * C1;
      const f32x2 aG = vG * C2;
      const f32x2 aO = vO * C1;
      f32x2 Ae, Be, Ge, Oe;
      Ae.x = __builtin_amdgcn_exp2f(aF.x); Ae.y = __builtin_amdgcn_exp2f(aF.y);
      Be.x = __builtin_amdgcn_exp2f(aI.x); Be.y = __builtin_amdgcn_exp2f(aI.y);
      Ge.x = __builtin_amdgcn_exp2f(aG.x); Ge.y = __builtin_amdgcn_exp2f(aG.y);
      Oe.x = __builtin_amdgcn_exp2f(aO.x); Oe.y = __builtin_amdgcn_exp2f(aO.y);
      const f32x2 M1 = (onep + Be) * (onep + Ge);
      const f32x2 t2 = onep + Ae;
      const f32x2 nm = cc2[p] * M1 + (onep - Ge) * t2;
      const f32x2 den = t2 * M1;
      f32x2 rd; rd.x = __builtin_amdgcn_rcpf(den.x); rd.y = __builtin_amdgcn_rcpf(den.y);
      const f32x2 cn = nm * rd;
      cc2[p] = cn;
      const f32x2 aE = cn * C2;
      f32x2 Ee; Ee.x = __builtin_amdgcn_exp2f(aE.x); Ee.y = __builtin_amdgcn_exp2f(aE.y);
      const f32x2 dh = (onep + Ee) * (onep + Oe);
      f32x2 rh; rh.x = __builtin_amdgcn_rcpf(dh.x); rh.y = __builtin_amdgcn_rcpf(dh.y);
      const f32x2 hv = (onep - Ee) * rh;
      w2[p] = (unsigned int)f2bf(hv.x) | ((unsigned int)f2bf(hv.y) << 16);
    }
    uint2 pk; pk.x = w2[0]; pk.y = w2[1];
    *(uint2*)(dst + hOffW) = pk;
  };

  unsigned short* H0 = &A0[0][0];    // after encoder: h0(1023)
  unsigned short* H1 = &A1[1][0];    // after encoder: h1(1023)

  if (isA) {
    // ================= layer-0 engine =================
    bf16x8 WA[12];
#pragma unroll
    for (int gt = 0; gt < 4; ++gt) {
      const int col = 64 * gt + u;
      WA[gt * 3 + 0] = ld8(Whh0v, col * HDIM + 8 * q);       // A-frag: W[unit][k]
      WA[gt * 3 + 1] = ld8(Whh0v, col * HDIM + 32 + 8 * q);
      union { unsigned short us[8]; bf16x8 v; } t2;
#pragma unroll
      for (int j = 0; j < 8; ++j) t2.us[j] = 0;
      if (q == 0) {
#pragma unroll
        for (int j = 0; j < INDIM; ++j) t2.us[j] = f2bf(ld1(Wih0v, col * INDIM + j));
      }
      WA[gt * 3 + 2] = t2.v;
    }

    int t0v = 0;
    for (int i = 0; i <= T_SEQ; ++i) {
      if (i > 0 && i < T_SEQ && (i & (CHNK - 1)) == 0) {
        load_chunk(i);            // prior step's XB2 reads are behind last barrier
        __syncthreads();
        t0v = i;
      }
      const int cur = i & 1;
      if (i < T_SEQ) {
        const unsigned short* A0c = &A0[cur][0];
        unsigned short*       A0n = &A0[cur ^ 1][0];
        const bf16x8 f0 = *(const bf16x8*)(A0c + aOff);
        const bf16x8 f1 = *(const bf16x8*)(A0c + aOff + 32);
        const bf16x8 f2 = *(const bf16x8*)(xsrc_at(i - t0v));
        // bias C-init from LDS each step (laundered index defeats hoisting):
        // ds_read_b128 lands directly in the accumulator regs -> no v_movs.
        unsigned boffL = bOff; asm volatile("" : "+v"(boffL));
        const f32x4 b0 = *(const f32x4*)(&BS0[0 * 64 + boffL]);
        const f32x4 b1 = *(const f32x4*)(&BS0[1 * 64 + boffL]);
        const f32x4 b2 = *(const f32x4*)(&BS0[2 * 64 + boffL]);
        const f32x4 b3 = *(const f32x4*)(&BS0[3 * 64 + boffL]);
        __builtin_amdgcn_s_setprio(1);
        f32x4 g0 = MFMA16(WA[0], f0, b0); g0 = MFMA16(WA[1],  f1, g0); g0 = MFMA16(WA[2],  f2, g0);
        f32x4 g1 = MFMA16(WA[3], f0, b1); g1 = MFMA16(WA[4],  f1, g1); g1 = MFMA16(WA[5],  f2, g1);
        f32x4 g2 = MFMA16(WA[6], f0, b2); g2 = MFMA16(WA[7],  f1, g2); g2 = MFMA16(WA[8],  f2, g2);
        f32x4 g3 = MFMA16(WA[9], f0, b3); g3 = MFMA16(WA[10], f1, g3); g3 = MFMA16(WA[11], f2, g3);
        __builtin_amdgcn_s_setprio(0);
        act4(g0, g1, g2, g3, A0n);
      }
      __syncthreads();
    }
    // seed decoder x feedback with x(1023) (last chunk t0v=896, tc=127)
    if (tid < 96)
      XD[dxr * 8 + dxk] = XB2[((size_t)dxr * CHNK + (127 ^ (dxr & 7))) * 8 + dxk];
    __syncthreads();
    // decoder, engine A (4 barriers/step, mirrored in B)
    for (int d = 0; d < NPRED; ++d) {
      const bf16x8 fa0 = *(const bf16x8*)(H0 + aOff);
      const bf16x8 fa1 = *(const bf16x8*)(H0 + aOff + 32);
      const bf16x8 fa2 = *(const bf16x8*)((q == 0) ? ((const char*)XD + n * 16)
                                                   : (const char*)ZPAD);
      __syncthreads();                      // ph1
      {
        unsigned boffL = bOff; asm volatile("" : "+v"(boffL));
        const f32x4 b0 = *(const f32x4*)(&BS0[0 * 64 + boffL]);
        const f32x4 b1 = *(const f32x4*)(&BS0[1 * 64 + boffL]);
        const f32x4 b2 = *(const f32x4*)(&BS0[2 * 64 + boffL]);
        const f32x4 b3 = *(const f32x4*)(&BS0[3 * 64 + boffL]);
        f32x4 g0 = MFMA16(WA[0], fa0, b0); g0 = MFMA16(WA[1],  fa1, g0); g0 = MFMA16(WA[2],  fa2, g0);
        f32x4 g1 = MFMA16(WA[3], fa0, b1); g1 = MFMA16(WA[4],  fa1, g1); g1 = MFMA16(WA[5],  fa2, g1);
        f32x4 g2 = MFMA16(WA[6], fa0, b2); g2 = MFMA16(WA[7],  fa1, g2); g2 = MFMA16(WA[8],  fa2, g2);
        f32x4 g3 = MFMA16(WA[9], fa0, b3); g3 = MFMA16(WA[10], fa1, g3); g3 = MFMA16(WA[11], fa2, g3);
        act4(g0, g1, g2, g3, H0);
      }
      __syncthreads();                      // ph2
      __syncthreads();                      // ph3 (B computes h1)
      if (tid < 96) {                       // ph4: FC head + feedback
        const unsigned short* h1row = H1 + dxr * S0;
        const int4* hp = (const int4*)h1row;
        const int4* wp = (const int4*)(&FCW[dxk * HDIM]);
        float s = FCB[dxk];
#pragma unroll
        for (int i8 = 0; i8 < 8; ++i8) {
          const int4 hv = hp[i8];
          const int4 wv2 = wp[i8];
          const unsigned int hu[4] = {(unsigned)hv.x, (unsigned)hv.y, (unsigned)hv.z, (unsigned)hv.w};
          const unsigned int wu[4] = {(unsigned)wv2.x, (unsigned)wv2.y, (unsigned)wv2.z, (unsigned)wv2.w};
#pragma unroll
          for (int k2 = 0; k2 < 4; ++k2) {
            union { unsigned int uu; float ff; } hl, hh2, wl, wh;
            hl.uu = hu[k2] << 16; hh2.uu = hu[k2] & 0xFFFF0000u;
            wl.uu = wu[k2] << 16; wh.uu  = wu[k2] & 0xFFFF0000u;
            s += hl.ff * wl.ff + hh2.ff * wh.ff;
          }
        }
        const unsigned short pb = f2bf(s);
        const size_t idx = (size_t)(rbase + dxr) * (NPRED * INDIM) + (size_t)d * INDIM + dxk;
        if constexpr (F32) ((float*)outv)[idx] = s;
        else               ((unsigned short*)outv)[idx] = pb;
        XD[dxr * 8 + dxk] = pb;
      }
      __syncthreads();                      // ph4 end
    }
  } else {
    // ================= layer-1 engine (lag 1) =================
    bf16x8 WB[16];
#pragma unroll
    for (int gt = 0; gt < 4; ++gt) {
      const int col = 64 * gt + u;
      WB[gt * 4 + 0] = ld8(Wih1v, col * HDIM + 8 * q);
      WB[gt * 4 + 1] = ld8(Wih1v, col * HDIM + 32 + 8 * q);
      WB[gt * 4 + 2] = ld8(Whh1v, col * HDIM + 8 * q);
      WB[gt * 4 + 3] = ld8(Whh1v, col * HDIM + 32 + 8 * q);
    }

    for (int i = 0; i <= T_SEQ; ++i) {
      if (i > 0 && i < T_SEQ && (i & (CHNK - 1)) == 0) {
        load_chunk(i);
        __syncthreads();
      }
      const int cur = i & 1;
      if (i >= 1) {
        const unsigned short* A0c = &A0[cur][0];
        const unsigned short* A1c = &A1[cur][0];
        unsigned short*       A1n = &A1[cur ^ 1][0];
        const bf16x8 h0a = *(const bf16x8*)(A0c + aOff);
        const bf16x8 h0b = *(const bf16x8*)(A0c + aOff + 32);
        const bf16x8 r0  = *(const bf16x8*)(A1c + aOff);
        const bf16x8 r1  = *(const bf16x8*)(A1c + aOff + 32);
        unsigned boffL = bOff; asm volatile("" : "+v"(boffL));
        const f32x4 b0 = *(const f32x4*)(&BS1[0 * 64 + boffL]);
        const f32x4 b1 = *(const f32x4*)(&BS1[1 * 64 + boffL]);
        const f32x4 b2 = *(const f32x4*)(&BS1[2 * 64 + boffL]);
        const f32x4 b3 = *(const f32x4*)(&BS1[3 * 64 + boffL]);
        __builtin_amdgcn_s_setprio(1);
        f32x4 g0 = MFMA16(WB[0],  h0a, b0); g0 = MFMA16(WB[1],  h0b, g0); g0 = MFMA16(WB[2],  r0, g0); g0 = MFMA16(WB[3],  r1, g0);
        f32x4 g1 = MFMA16(WB[4],  h0a, b1); g1 = MFMA16(WB[5],  h0b, g1); g1 = MFMA16(WB[6],  r0, g1); g1 = MFMA16(WB[7],  r1, g1);
        f32x4 g2 = MFMA16(WB[8],  h0a, b2); g2 = MFMA16(WB[9],  h0b, g2); g2 = MFMA16(WB[10], r0, g2); g2 = MFMA16(WB[11], r1, g2);
        f32x4 g3 = MFMA16(WB[12], h0a, b3); g3 = MFMA16(WB[13], h0b, g3); g3 = MFMA16(WB[14], r0, g3); g3 = MFMA16(WB[15], r1, g3);
        __builtin_amdgcn_s_setprio(0);
        act4(g0, g1, g2, g3, A1n);
      }
      __syncthreads();
    }
    __syncthreads();   // matches A's XD-seed barrier
    // decoder, engine B (4 barriers/step, mirrored with A)
    for (int d = 0; d < NPRED; ++d) {
      const bf16x8 fr0 = *(const bf16x8*)(H1 + aOff);
      const bf16x8 fr1 = *(const bf16x8*)(H1 + aOff + 32);
      __syncthreads();                      // ph1
      __syncthreads();                      // ph2 (A computes h0)
      {
        const bf16x8 h0a = *(const bf16x8*)(H0 + aOff);
        const bf16x8 h0b = *(const bf16x8*)(H0 + aOff + 32);
        unsigned boffL = bOff; asm volatile("" : "+v"(boffL));
        const f32x4 b0 = *(const f32x4*)(&BS1[0 * 64 + boffL]);
        const f32x4 b1 = *(const f32x4*)(&BS1[1 * 64 + boffL]);
        const f32x4 b2 = *(const f32x4*)(&BS1[2 * 64 + boffL]);
        const f32x4 b3 = *(const f32x4*)(&BS1[3 * 64 + boffL]);
        f32x4 g0 = MFMA16(WB[0],  h0a, b0); g0 = MFMA16(WB[1],  h0b, g0); g0 = MFMA16(WB[2],  fr0, g0); g0 = MFMA16(WB[3],  fr1, g0);
        f32x4 g1 = MFMA16(WB[4],  h0a, b1); g1 = MFMA16(WB[5],  h0b, g1); g1 = MFMA16(WB[6],  fr0, g1); g1 = MFMA16(WB[7],  fr1, g1);
        f32x4 g2 = MFMA16(WB[8],  h0a, b2); g2 = MFMA16(WB[9],  h0b, g2); g2 = MFMA16(WB[10], fr0, g2); g2 = MFMA16(WB[11], fr1, g2);
        f32x4 g3 = MFMA16(WB[12], h0a, b3); g3 = MFMA16(WB[13], h0b, g3); g3 = MFMA16(WB[14], fr0, g3); g3 = MFMA16(WB[15], fr1, g3);
        act4(g0, g1, g2, g3, H1);
      }
      __syncthreads();                      // ph3
      __syncthreads();                      // ph4 (A does FC head)
    }
  }
}

extern "C" void kernel_launch(void* const* d_in, const int* in_sizes, int n_in,
                              void* d_out, int out_size, void* d_ws, size_t ws_size,
                              hipStream_t stream) {
  (void)d_ws; (void)ws_size; (void)out_size;
  const void* x    = d_in[0];
  const void* Wih0 = d_in[1];
  const void* Whh0 = d_in[2];
  const void* bih0 = d_in[3];
  const void* bhh0 = d_in[4];
  const void* Wih1 = d_in[5];
  const void* Whh1 = d_in[6];
  const void* bih1 = d_in[7];
  const void* bhh1 = d_in[8];
  const void* fcw  = d_in[9];
  const void* fcb  = d_in[10];
  // Host-side dtype dispatch via Wih0 byte size (4*H*IN elems):
  //   f32 = 6144 B, bf16 = 3072 B. Falls back to the proven dual-launch
  //   (device-side sniff keeps exactly one instance active) if ambiguous.
  const int wb = (in_sizes && n_in >= 11) ? in_sizes[1] : 0;
  if (wb == 4 * HDIM * INDIM * 4) {
    lstm2_pipe<true><<<dim3(4096 / NROWS), dim3(512), 0, stream>>>(
        x, Wih0, Whh0, bih0, bhh0, Wih1, Whh1, bih1, bhh1, fcw, fcb, d_out);
  } else if (wb == 4 * HDIM * INDIM * 2) {
    lstm2_pipe<false><<<dim3(4096 / NROWS), dim3(512), 0, stream>>>(
        x, Wih0, Whh0, bih0, bhh0, Wih1, Whh1, bih1, bhh1, fcw, fcb, d_out);
  } else {
    lstm2_pipe<true><<<dim3(4096 / NROWS), dim3(512), 0, stream>>>(
        x, Wih0, Whh0, bih0, bhh0, Wih1, Whh1, bih1, bhh1, fcw, fcb, d_out);
    lstm2_pipe<false><<<dim3(4096 / NROWS), dim3(512), 0, stream>>>(
        x, Wih0, Whh0, bih0, bhh0, Wih1, Whh1, bih1, bhh1, fcw, fcb, d_out);
  }
}

// Round 8
// 876.231 us; speedup vs baseline: 1.9848x; 1.1477x over previous
//
#include <hip/hip_runtime.h>

#define T_SEQ   1024
#define INDIM   6
#define HDIM    64
#define NPRED   10
#define CHNK    128
#define S0      72       // LDS row stride (elements) for h buffers (h-only)
#define NROWS   16       // batch rows per workgroup (grid 256 = 1 block/CU)

typedef __bf16         bf16x8 __attribute__((ext_vector_type(8)));
typedef float          f32x4  __attribute__((ext_vector_type(4)));
typedef float          f32x2  __attribute__((ext_vector_type(2)));
typedef unsigned short us4    __attribute__((ext_vector_type(4)));

// D = A*B + C with A = weight frag, B = h frag  ->  D[m=unit][n=batch row]
#define MFMA16(a, b, c) __builtin_amdgcn_mfma_f32_16x16x32_bf16((a), (b), (c), 0, 0, 0)

static __device__ __forceinline__ float bf2f(unsigned short b) {
  union { unsigned int u; float f; } v; v.u = ((unsigned int)b) << 16; return v.f;
}
// Native RNE f32->bf16 (ISel pairs these into v_cvt_pk_bf16_f32 on gfx950).
static __device__ __forceinline__ unsigned short f2bf(float f) {
  union { __bf16 b; unsigned short u; } v; v.b = (__bf16)f; return v.u;
}

// R8 = R5 exact (best measured: 848 us) + host-side dtype dispatch only.
// R7's bias-from-LDS is REVERTED: it put 4 ds_read_b128 (~120cy LDS latency)
// on the per-step MFMA C-operand chain -> +19%. Bias lives in registers.
// Device sniff retained as guard for the dual-launch fallback path.
// Bit-exact canary: absmax must stay 0.0009765625.
template <bool F32>
__global__ __launch_bounds__(512, 2)
void lstm2_pipe(const void* __restrict__ xv,
                const void* __restrict__ Wih0v,
                const void* __restrict__ Whh0v,
                const void* __restrict__ bih0v,
                const void* __restrict__ bhh0v,
                const void* __restrict__ Wih1v,
                const void* __restrict__ Whh1v,
                const void* __restrict__ bih1v,
                const void* __restrict__ bhh1v,
                const void* __restrict__ fcwv,
                const void* __restrict__ fcbv,
                void* __restrict__ outv)
{
  // ---- dtype sniff (uniform; guards the dual-launch fallback path) ----
  {
    const unsigned short* w0u = (const unsigned short*)Wih0v;
    int votes = 0;
#pragma unroll
    for (int i = 0; i < 16; ++i) {
      const unsigned e = (w0u[2 * i] >> 7) & 0xFF;
      votes += (e >= 0x80 || e <= 0x40) ? 1 : 0;
    }
    if ((votes >= 4) != F32) return;
  }

  // A0[b]: [row][k]: k 0..63 = h0 (unit-major), 64..71 pad.
  __shared__ __align__(16) unsigned short A0[2][NROWS * S0];
  __shared__ __align__(16) unsigned short A1[2][NROWS * S0];
  __shared__ __align__(16) unsigned short XB2[NROWS * CHNK * 8];  // [row][t^(row&7)][8]
  __shared__ __align__(16) unsigned short XD[NROWS * 8];          // decoder x feedback
  __shared__ __align__(16) unsigned short ZPAD[8];                // 16B of zeros
  __shared__ __align__(16) unsigned short FCW[INDIM * HDIM];
  __shared__ float FCB[INDIM];

  const int tid   = threadIdx.x;
  const int lane  = tid & 63;
  const int wave  = tid >> 6;
  const bool isA  = (wave < 4);
  const int  wv4  = wave & 3;
  const int  q    = lane >> 4;
  const int  n    = lane & 15;          // batch row owned by this lane (D col)
  const int  u    = 16 * wv4 + n;       // index used for W/bias row addressing
  const int rbase = blockIdx.x * NROWS;

  {
    unsigned short* p0 = &A0[0][0];
    unsigned short* p1 = &A1[0][0];
    for (int i = tid; i < 2 * NROWS * S0; i += 512) { p0[i] = 0; p1[i] = 0; }
    for (int i = tid; i < NROWS * 8; i += 512) XD[i] = 0;
    if (tid < 8) ZPAD[tid] = 0;
  }
  for (int i = tid; i < INDIM * HDIM; i += 512) {
    if constexpr (F32) FCW[i] = f2bf(((const float*)fcwv)[i]);
    else               FCW[i] = ((const unsigned short*)fcwv)[i];
  }
  if (tid < INDIM) {
    if constexpr (F32) FCB[tid] = ((const float*)fcbv)[tid];
    else               FCB[tid] = bf2f(((const unsigned short*)fcbv)[tid]);
  }

  auto ld1 = [&](const void* p, int i) -> float {
    if constexpr (F32) return ((const float*)p)[i];
    else               return bf2f(((const unsigned short*)p)[i]);
  };
  auto ld8 = [&](const void* W, int off) -> bf16x8 {
    union { unsigned short us[8]; bf16x8 v; } t;
    if constexpr (F32) {
      const float* p = (const float*)W + off;
#pragma unroll
      for (int j = 0; j < 8; ++j) t.us[j] = f2bf(p[j]);
    } else {
      t.v = *(const bf16x8*)((const unsigned short*)W + off);
    }
    return t.v;
  };

  // stage chunk [t0c, t0c+CHNK) into XB2: per (row,t): 6 x-values + 2 zeros,
  // swizzled slot t^(row&7). t fast-varying across lanes -> coalesced global.
  auto load_chunk = [&](int t0c) {
    for (int c = tid; c < NROWS * CHNK; c += 512) {
      const int row = c >> 7;          // 0..15
      const int t   = c & (CHNK - 1);  // 0..127
      int4 o;
      if constexpr (F32) {
        const float* p = (const float*)xv + ((size_t)(rbase + row) * T_SEQ + (t0c + t)) * INDIM;
        const float2 v0 = *(const float2*)(p);
        const float2 v1 = *(const float2*)(p + 2);
        const float2 v2 = *(const float2*)(p + 4);
        union { unsigned short us[8]; int4 v; } tt;
        tt.us[0] = f2bf(v0.x); tt.us[1] = f2bf(v0.y);
        tt.us[2] = f2bf(v1.x); tt.us[3] = f2bf(v1.y);
        tt.us[4] = f2bf(v2.x); tt.us[5] = f2bf(v2.y);
        tt.us[6] = 0;          tt.us[7] = 0;
        o = tt.v;
      } else {
        const unsigned short* p = (const unsigned short*)xv
            + ((size_t)(rbase + row) * T_SEQ + (t0c + t)) * INDIM;
        o.x = *(const unsigned int*)(p);
        o.y = *(const unsigned int*)(p + 2);
        o.z = *(const unsigned int*)(p + 4);
        o.w = 0;
      }
      *(int4*)((char*)XB2 + (((size_t)row * CHNK) + (t ^ (row & 7))) * 16) = o;
    }
  };

  load_chunk(0);

  // decoder FC/feedback mapping (tid-based, barrier-protected)
  const int dxr = tid / INDIM;                 // valid for tid < 96
  const int dxk = tid - dxr * INDIM;

  __syncthreads();   // covers zero-init + FCW + chunk 0

  const int aOff  = n * S0 + 8 * q;               // h frag (B-operand): row n, k 8q..
  const int hOffW = n * S0 + 16 * wv4 + 4 * q;    // packed h-write: row n, units 4q..4q+3
  const int bOff  = 16 * wv4 + 4 * q;             // bias vector base within gate block

  // x B-operand source: q==0 lanes read XB2 row n (swizzled), q>0 broadcast ZPAD
  auto xsrc_at = [&](int tc) -> const char* {
    return (q == 0)
        ? ((const char*)XB2 + (((size_t)n * CHNK) + (tc ^ (n & 7))) * 16)
        : (const char*)ZPAD;
  };

  // cell state as two f32 pairs (cells 0,1 | 2,3) so act math stays packed
  f32x2 cc2[2]; cc2[0] = (f32x2){0.f, 0.f}; cc2[1] = (f32x2){0.f, 0.f};

  // bias vector for gate block gt: b[64gt + bOff .. +3]
  auto ldbias = [&](const void* b1, const void* b2, int gt) -> f32x4 {
    f32x4 r;
#pragma unroll
    for (int j = 0; j < 4; ++j)
      r[j] = ld1(b1, 64 * gt + bOff + j) + ld1(b2, 64 * gt + bOff + j);
    return r;
  };

  // 7-trans combined-rcp cell update, packed-f32 (v_pk_*) elementwise math,
  // native cvt_pk bf16 packing, one b64 h-write.
  const f32x2 C1   = {-1.442695040888963f, -1.442695040888963f};
  const f32x2 C2   = {-2.885390081777927f, -2.885390081777927f};
  const f32x2 onep = {1.0f, 1.0f};

  auto act4 = [&](const f32x4 gI, const f32x4 gF, const f32x4 gG, const f32x4 gO,
                  unsigned short* dst) {
    unsigned int w2[2];
#pragma unroll
    for (int p = 0; p < 2; ++p) {
      f32x2 vI, vF, vG, vO;
      vI.x = gI[2 * p]; vI.y = gI[2 * p + 1];
      vF.x = gF[2 * p]; vF.y = gF[2 * p + 1];
      vG.x = gG[2 * p]; vG.y = gG[2 * p + 1];
      vO.x = gO[2 * p]; vO.y = gO[2 * p + 1];
      const f32x2 aF = vF * C1;
      const f32x2 aI = vI * C1;
      const f32x2 aG = vG * C2;
      const f32x2 aO = vO * C1;
      f32x2 Ae, Be, Ge, Oe;
      Ae.x = __builtin_amdgcn_exp2f(aF.x); Ae.y = __builtin_amdgcn_exp2f(aF.y);
      Be.x = __builtin_amdgcn_exp2f(aI.x); Be.y = __builtin_amdgcn_exp2f(aI.y);
      Ge.x = __builtin_amdgcn_exp2f(aG.x); Ge.y = __builtin_amdgcn_exp2f(aG.y);
      Oe.x = __builtin_amdgcn_exp2f(aO.x); Oe.y = __builtin_amdgcn_exp2f(aO.y);
      const f32x2 M1 = (onep + Be) * (onep + Ge);
      const f32x2 t2 = onep + Ae;
      const f32x2 nm = cc2[p] * M1 + (onep - Ge) * t2;
      const f32x2 den = t2 * M1;
      f32x2 rd; rd.x = __builtin_amdgcn_rcpf(den.x); rd.y = __builtin_amdgcn_rcpf(den.y);
      const f32x2 cn = nm * rd;
      cc2[p] = cn;
      const f32x2 aE = cn * C2;
      f32x2 Ee; Ee.x = __builtin_amdgcn_exp2f(aE.x); Ee.y = __builtin_amdgcn_exp2f(aE.y);
      const f32x2 dh = (onep + Ee) * (onep + Oe);
      f32x2 rh; rh.x = __builtin_amdgcn_rcpf(dh.x); rh.y = __builtin_amdgcn_rcpf(dh.y);
      const f32x2 hv = (onep - Ee) * rh;
      w2[p] = (unsigned int)f2bf(hv.x) | ((unsigned int)f2bf(hv.y) << 16);
    }
    uint2 pk; pk.x = w2[0]; pk.y = w2[1];
    *(uint2*)(dst + hOffW) = pk;
  };

  unsigned short* H0 = &A0[0][0];    // after encoder: h0(1023)
  unsigned short* H1 = &A1[1][0];    // after encoder: h1(1023)

  if (isA) {
    // ================= layer-0 engine =================
    bf16x8 WA[12]; f32x4 bvA[4];
#pragma unroll
    for (int gt = 0; gt < 4; ++gt) {
      const int col = 64 * gt + u;
      WA[gt * 3 + 0] = ld8(Whh0v, col * HDIM + 8 * q);       // A-frag: W[unit][k]
      WA[gt * 3 + 1] = ld8(Whh0v, col * HDIM + 32 + 8 * q);
      union { unsigned short us[8]; bf16x8 v; } t2;
#pragma unroll
      for (int j = 0; j < 8; ++j) t2.us[j] = 0;
      if (q == 0) {
#pragma unroll
        for (int j = 0; j < INDIM; ++j) t2.us[j] = f2bf(ld1(Wih0v, col * INDIM + j));
      }
      WA[gt * 3 + 2] = t2.v;
      bvA[gt] = ldbias(bih0v, bhh0v, gt);
    }

    int t0v = 0;
    for (int i = 0; i <= T_SEQ; ++i) {
      if (i > 0 && i < T_SEQ && (i & (CHNK - 1)) == 0) {
        load_chunk(i);            // prior step's XB2 reads are behind last barrier
        __syncthreads();
        t0v = i;
      }
      const int cur = i & 1;
      if (i < T_SEQ) {
        const unsigned short* A0c = &A0[cur][0];
        unsigned short*       A0n = &A0[cur ^ 1][0];
        const bf16x8 f0 = *(const bf16x8*)(A0c + aOff);
        const bf16x8 f1 = *(const bf16x8*)(A0c + aOff + 32);
        const bf16x8 f2 = *(const bf16x8*)(xsrc_at(i - t0v));
        __builtin_amdgcn_s_setprio(1);
        f32x4 g0 = MFMA16(WA[0], f0, bvA[0]); g0 = MFMA16(WA[1],  f1, g0); g0 = MFMA16(WA[2],  f2, g0);
        f32x4 g1 = MFMA16(WA[3], f0, bvA[1]); g1 = MFMA16(WA[4],  f1, g1); g1 = MFMA16(WA[5],  f2, g1);
        f32x4 g2 = MFMA16(WA[6], f0, bvA[2]); g2 = MFMA16(WA[7],  f1, g2); g2 = MFMA16(WA[8],  f2, g2);
        f32x4 g3 = MFMA16(WA[9], f0, bvA[3]); g3 = MFMA16(WA[10], f1, g3); g3 = MFMA16(WA[11], f2, g3);
        __builtin_amdgcn_s_setprio(0);
        act4(g0, g1, g2, g3, A0n);
      }
      __syncthreads();
    }
    // seed decoder x feedback with x(1023) (last chunk t0v=896, tc=127)
    if (tid < 96)
      XD[dxr * 8 + dxk] = XB2[((size_t)dxr * CHNK + (127 ^ (dxr & 7))) * 8 + dxk];
    __syncthreads();
    // decoder, engine A (4 barriers/step, mirrored in B)
    for (int d = 0; d < NPRED; ++d) {
      const bf16x8 fa0 = *(const bf16x8*)(H0 + aOff);
      const bf16x8 fa1 = *(const bf16x8*)(H0 + aOff + 32);
      const bf16x8 fa2 = *(const bf16x8*)((q == 0) ? ((const char*)XD + n * 16)
                                                   : (const char*)ZPAD);
      __syncthreads();                      // ph1
      {
        f32x4 g0 = MFMA16(WA[0], fa0, bvA[0]); g0 = MFMA16(WA[1],  fa1, g0); g0 = MFMA16(WA[2],  fa2, g0);
        f32x4 g1 = MFMA16(WA[3], fa0, bvA[1]); g1 = MFMA16(WA[4],  fa1, g1); g1 = MFMA16(WA[5],  fa2, g1);
        f32x4 g2 = MFMA16(WA[6], fa0, bvA[2]); g2 = MFMA16(WA[7],  fa1, g2); g2 = MFMA16(WA[8],  fa2, g2);
        f32x4 g3 = MFMA16(WA[9], fa0, bvA[3]); g3 = MFMA16(WA[10], fa1, g3); g3 = MFMA16(WA[11], fa2, g3);
        act4(g0, g1, g2, g3, H0);
      }
      __syncthreads();                      // ph2
      __syncthreads();                      // ph3 (B computes h1)
      if (tid < 96) {                       // ph4: FC head + feedback
        const unsigned short* h1row = H1 + dxr * S0;
        const int4* hp = (const int4*)h1row;
        const int4* wp = (const int4*)(&FCW[dxk * HDIM]);
        float s = FCB[dxk];
#pragma unroll
        for (int i8 = 0; i8 < 8; ++i8) {
          const int4 hv = hp[i8];
          const int4 wv2 = wp[i8];
          const unsigned int hu[4] = {(unsigned)hv.x, (unsigned)hv.y, (unsigned)hv.z, (unsigned)hv.w};
          const unsigned int wu[4] = {(unsigned)wv2.x, (unsigned)wv2.y, (unsigned)wv2.z, (unsigned)wv2.w};
#pragma unroll
          for (int k2 = 0; k2 < 4; ++k2) {
            union { unsigned int uu; float ff; } hl, hh2, wl, wh;
            hl.uu = hu[k2] << 16; hh2.uu = hu[k2] & 0xFFFF0000u;
            wl.uu = wu[k2] << 16; wh.uu  = wu[k2] & 0xFFFF0000u;
            s += hl.ff * wl.ff + hh2.ff * wh.ff;
          }
        }
        const unsigned short pb = f2bf(s);
        const size_t idx = (size_t)(rbase + dxr) * (NPRED * INDIM) + (size_t)d * INDIM + dxk;
        if constexpr (F32) ((float*)outv)[idx] = s;
        else               ((unsigned short*)outv)[idx] = pb;
        XD[dxr * 8 + dxk] = pb;
      }
      __syncthreads();                      // ph4 end
    }
  } else {
    // ================= layer-1 engine (lag 1) =================
    bf16x8 WB[16]; f32x4 bvB[4];
#pragma unroll
    for (int gt = 0; gt < 4; ++gt) {
      const int col = 64 * gt + u;
      WB[gt * 4 + 0] = ld8(Wih1v, col * HDIM + 8 * q);
      WB[gt * 4 + 1] = ld8(Wih1v, col * HDIM + 32 + 8 * q);
      WB[gt * 4 + 2] = ld8(Whh1v, col * HDIM + 8 * q);
      WB[gt * 4 + 3] = ld8(Whh1v, col * HDIM + 32 + 8 * q);
      bvB[gt] = ldbias(bih1v, bhh1v, gt);
    }

    for (int i = 0; i <= T_SEQ; ++i) {
      if (i > 0 && i < T_SEQ && (i & (CHNK - 1)) == 0) {
        load_chunk(i);
        __syncthreads();
      }
      const int cur = i & 1;
      if (i >= 1) {
        const unsigned short* A0c = &A0[cur][0];
        const unsigned short* A1c = &A1[cur][0];
        unsigned short*       A1n = &A1[cur ^ 1][0];
        const bf16x8 h0a = *(const bf16x8*)(A0c + aOff);
        const bf16x8 h0b = *(const bf16x8*)(A0c + aOff + 32);
        const bf16x8 r0  = *(const bf16x8*)(A1c + aOff);
        const bf16x8 r1  = *(const bf16x8*)(A1c + aOff + 32);
        __builtin_amdgcn_s_setprio(1);
        f32x4 g0 = MFMA16(WB[0],  h0a, bvB[0]); g0 = MFMA16(WB[1],  h0b, g0); g0 = MFMA16(WB[2],  r0, g0); g0 = MFMA16(WB[3],  r1, g0);
        f32x4 g1 = MFMA16(WB[4],  h0a, bvB[1]); g1 = MFMA16(WB[5],  h0b, g1); g1 = MFMA16(WB[6],  r0, g1); g1 = MFMA16(WB[7],  r1, g1);
        f32x4 g2 = MFMA16(WB[8],  h0a, bvB[2]); g2 = MFMA16(WB[9],  h0b, g2); g2 = MFMA16(WB[10], r0, g2); g2 = MFMA16(WB[11], r1, g2);
        f32x4 g3 = MFMA16(WB[12], h0a, bvB[3]); g3 = MFMA16(WB[13], h0b, g3); g3 = MFMA16(WB[14], r0, g3); g3 = MFMA16(WB[15], r1, g3);
        __builtin_amdgcn_s_setprio(0);
        act4(g0, g1, g2, g3, A1n);
      }
      __syncthreads();
    }
    __syncthreads();   // matches A's XD-seed barrier
    // decoder, engine B (4 barriers/step, mirrored with A)
    for (int d = 0; d < NPRED; ++d) {
      const bf16x8 fr0 = *(const bf16x8*)(H1 + aOff);
      const bf16x8 fr1 = *(const bf16x8*)(H1 + aOff + 32);
      __syncthreads();                      // ph1
      __syncthreads();                      // ph2 (A computes h0)
      {
        const bf16x8 h0a = *(const bf16x8*)(H0 + aOff);
        const bf16x8 h0b = *(const bf16x8*)(H0 + aOff + 32);
        f32x4 g0 = MFMA16(WB[0],  h0a, bvB[0]); g0 = MFMA16(WB[1],  h0b, g0); g0 = MFMA16(WB[2],  fr0, g0); g0 = MFMA16(WB[3],  fr1, g0);
        f32x4 g1 = MFMA16(WB[4],  h0a, bvB[1]); g1 = MFMA16(WB[5],  h0b, g1); g1 = MFMA16(WB[6],  fr0, g1); g1 = MFMA16(WB[7],  fr1, g1);
        f32x4 g2 = MFMA16(WB[8],  h0a, bvB[2]); g2 = MFMA16(WB[9],  h0b, g2); g2 = MFMA16(WB[10], fr0, g2); g2 = MFMA16(WB[11], fr1, g2);
        f32x4 g3 = MFMA16(WB[12], h0a, bvB[3]); g3 = MFMA16(WB[13], h0b, g3); g3 = MFMA16(WB[14], fr0, g3); g3 = MFMA16(WB[15], fr1, g3);
        act4(g0, g1, g2, g3, H1);
      }
      __syncthreads();                      // ph3
      __syncthreads();                      // ph4 (A does FC head)
    }
  }
}

extern "C" void kernel_launch(void* const* d_in, const int* in_sizes, int n_in,
                              void* d_out, int out_size, void* d_ws, size_t ws_size,
                              hipStream_t stream) {
  (void)d_ws; (void)ws_size; (void)out_size;
  const void* x    = d_in[0];
  const void* Wih0 = d_in[1];
  const void* Whh0 = d_in[2];
  const void* bih0 = d_in[3];
  const void* bhh0 = d_in[4];
  const void* Wih1 = d_in[5];
  const void* Whh1 = d_in[6];
  const void* bih1 = d_in[7];
  const void* bhh1 = d_in[8];
  const void* fcw  = d_in[9];
  const void* fcb  = d_in[10];
  // Host-side dtype dispatch via Wih0 byte size (4*H*IN elems):
  //   f32 = 6144 B, bf16 = 3072 B. Falls back to the proven dual-launch
  //   (device-side sniff keeps exactly one instance active) if ambiguous.
  const int wb = (in_sizes && n_in >= 11) ? in_sizes[1] : 0;
  if (wb == 4 * HDIM * INDIM * 4) {
    lstm2_pipe<true><<<dim3(4096 / NROWS), dim3(512), 0, stream>>>(
        x, Wih0, Whh0, bih0, bhh0, Wih1, Whh1, bih1, bhh1, fcw, fcb, d_out);
  } else if (wb == 4 * HDIM * INDIM * 2) {
    lstm2_pipe<false><<<dim3(4096 / NROWS), dim3(512), 0, stream>>>(
        x, Wih0, Whh0, bih0, bhh0, Wih1, Whh1, bih1, bhh1, fcw, fcb, d_out);
  } else {
    lstm2_pipe<true><<<dim3(4096 / NROWS), dim3(512), 0, stream>>>(
        x, Wih0, Whh0, bih0, bhh0, Wih1, Whh1, bih1, bhh1, fcw, fcb, d_out);
    lstm2_pipe<false><<<dim3(4096 / NROWS), dim3(512), 0, stream>>>(
        x, Wih0, Whh0, bih0, bhh0, Wih1, Whh1, bih1, bhh1, fcw, fcb, d_out);
  }
}